// Round 10
// baseline (99.884 us; speedup 1.0000x reference)
//
#include <hip/hip_runtime.h>
#include <hip/hip_bf16.h>

// ILA layer (fp32 I/O): key = W@ft, query = W@fk (1x1 conv, shared W),
// sim[p,k] = <query[p], key[neighbor_k(p)]> over 9x9 window (zero-padded keys),
// weight = softmax_k(sim)  (OOB entries participate with sim=0),
// out[c,p] = sum_k weight[k] * ft[c, neighbor_k(p)]  (zero-padded ft).
// n=2, c=128, h=w=64, L=9 (81 neighbors).
// K/Q intermediates are fp16 (same quantization the sim kernel already applied in LDS).

#define Hh 64
#define Ww 64
#define Cc 128
#define Nn 2
#define KK 81
#define HW (Hh * Ww)          // 4096
#define CHW (Cc * HW)         // 524288
#define P_TOT (Nn * HW)       // 8192

typedef _Float16 h8 __attribute__((ext_vector_type(8)));
typedef _Float16 h4 __attribute__((ext_vector_type(4)));
typedef _Float16 h2 __attribute__((ext_vector_type(2)));

__device__ __forceinline__ void fma4(float4& a, const float4 b, const float s) {
    a.x += b.x * s; a.y += b.y * s; a.z += b.z * s; a.w += b.w * s;
}

__device__ __forceinline__ float dot8(const h8 a, const h8 b, float acc) {
#if __has_builtin(__builtin_amdgcn_fdot2)
    h2 a0 = {a[0], a[1]}, b0 = {b[0], b[1]};
    h2 a1 = {a[2], a[3]}, b1 = {b[2], b[3]};
    h2 a2 = {a[4], a[5]}, b2 = {b[4], b[5]};
    h2 a3 = {a[6], a[7]}, b3 = {b[6], b[7]};
    acc = __builtin_amdgcn_fdot2(a0, b0, acc, false);
    acc = __builtin_amdgcn_fdot2(a1, b1, acc, false);
    acc = __builtin_amdgcn_fdot2(a2, b2, acc, false);
    acc = __builtin_amdgcn_fdot2(a3, b3, acc, false);
#else
#pragma unroll
    for (int i = 0; i < 8; ++i) acc += (float)a[i] * (float)b[i];
#endif
    return acc;
}

// ---------------- Kernel A: projection (K = W*ft, Q = W*fk), fp16 pixel-major out.
// 512 blocks x 256 thr; 16 px/block (2 blocks/CU = 2 waves/SIMD); tile = 4 px x 2 out.
__global__ __launch_bounds__(256) void proj_kernel(const float* __restrict__ ft,
                                                   const float* __restrict__ fk,
                                                   const float* __restrict__ Wm,
                                                   _Float16* __restrict__ Qbuf,
                                                   _Float16* __restrict__ Kbuf) {
    __shared__ __align__(16) float Wl[32 * 132];   // [ii][o] chunk of W^T
    __shared__ __align__(16) float xkl[128 * 20];  // [i][pl], pad 20
    __shared__ __align__(16) float xql[128 * 20];
    const int t = threadIdx.x;
    const int p0 = blockIdx.x * 16;       // 4096 % 16 == 0: never crosses n
    const int nn = p0 >> 12;
    const int gbase = nn * CHW + (p0 & 4095);

    for (int e = t; e < 128 * 16; e += 256) {       // stage x tiles (coalesced 64B runs)
        const int c = e >> 4, pl = e & 15;
        xkl[c * 20 + pl] = ft[gbase + c * HW + pl];
        xql[c * 20 + pl] = fk[gbase + c * HW + pl];
    }

    const int po = t & 3;                 // 4 pixel groups x 4 px
    const int oo = t >> 2;                // 64 out groups x 2 out
    float4 aK0 = make_float4(0,0,0,0), aK1 = aK0, aQ0 = aK0, aQ1 = aK0;

    for (int ch = 0; ch < 4; ++ch) {
        for (int e = t; e < 128 * 32; e += 256) {   // Wl[ii][o] <- Wm[o][ch*32+ii]
            const int o = e >> 5, ii = e & 31;
            Wl[ii * 132 + o] = Wm[o * 128 + (ch << 5) + ii];
        }
        __syncthreads();
#pragma unroll 4
        for (int ii = 0; ii < 32; ++ii) {
            const float2 w2 = *(const float2*)&Wl[ii * 132 + (oo << 1)];
            const float4 k4 = *(const float4*)&xkl[((ch << 5) + ii) * 20 + (po << 2)];
            const float4 q4 = *(const float4*)&xql[((ch << 5) + ii) * 20 + (po << 2)];
            fma4(aK0, k4, w2.x); fma4(aK1, k4, w2.y);
            fma4(aQ0, q4, w2.x); fma4(aQ1, q4, w2.y);
        }
        __syncthreads();
    }

    const float kx[4] = {aK0.x, aK0.y, aK0.z, aK0.w};
    const float ky[4] = {aK1.x, aK1.y, aK1.z, aK1.w};
    const float qx[4] = {aQ0.x, aQ0.y, aQ0.z, aQ0.w};
    const float qy[4] = {aQ1.x, aQ1.y, aQ1.z, aQ1.w};
#pragma unroll
    for (int pp = 0; pp < 4; ++pp) {      // h2 store: 256B contiguous per pixel across oo
        const size_t base = (size_t)(p0 + (po << 2) + pp) * 128 + (oo << 1);
        h2 kv; kv[0] = (_Float16)kx[pp]; kv[1] = (_Float16)ky[pp];
        h2 qv; qv[0] = (_Float16)qx[pp]; qv[1] = (_Float16)qy[pp];
        *(h2*)&Kbuf[base] = kv;
        *(h2*)&Qbuf[base] = qv;
    }
}

// ---------------- Kernel B (fused): sim + softmax + weighting. Block = 8-px row strip.
// K/Q arrive fp16 from proj; staged (XOR-swizzled) with straight h8 copies.
// LDS ~40 KB => 4 blocks/CU (16 waves/CU).
__global__ __launch_bounds__(256, 4) void sim_weight_kernel(const _Float16* __restrict__ Qbuf,
                                                            const _Float16* __restrict__ Kbuf,
                                                            const float* __restrict__ ft,
                                                            float* __restrict__ out) {
    __shared__ __align__(16) unsigned char smem[40464];
    _Float16* Ksw  = (_Float16*)smem;             // 18432 halves [0, 36864)
    _Float16* Qsw  = (_Float16*)(smem + 36864);   // 1024 halves  [36864, 38912)
    _Float16* ftl  = (_Float16*)smem;             // 19008 halves [0, 38016) — aliases Ksw/Qsw after B2
    _Float16* simb = (_Float16*)(smem + 38912);   // 648 halves   [38912, 40208)
    float*    redM = (float*)(smem + 40208);      // 32 floats
    float*    redS = (float*)(smem + 40336);      // 32 floats

    const int t  = threadIdx.x;
    const int b  = blockIdx.x;
    const int x0 = (b & 7) << 3;
    const int y  = (b >> 3) & 63;
    const int nn = b >> 9;
    const int pg0 = (nn << 12) + (y << 6) + x0;

    // ---- stage K: zero-padded 9x16 window, straight h8 copies, XOR-swizzled slots
#pragma unroll 3
    for (int e = t; e < 144 * 16; e += 256) {     // 2304 16B chunks
        const int v = e >> 4, ci = e & 15;
        const int gx = x0 + (v & 15) - 4;
        const int gy = y + (v >> 4) - 4;
        h8 val = {0, 0, 0, 0, 0, 0, 0, 0};
        if ((unsigned)gx < 64u && (unsigned)gy < 64u)
            val = *(const h8*)&Kbuf[(size_t)((nn << 12) + (gy << 6) + gx) * 128 + (ci << 3)];
        *(h8*)&Ksw[(v << 7) + ((ci ^ (v & 15)) << 3)] = val;
    }
    if (t < 128) {   // stage Q: 8 vectors x 16 chunks
        const int v = t >> 4, ci = t & 15;
        *(h8*)&Qsw[(v << 7) + ((ci ^ v) << 3)] =
            *(const h8*)&Qbuf[(size_t)(pg0 + v) * 128 + (ci << 3)];
    }
    __syncthreads();   // B1

    // ---- dots: thread -> (pixel p, k in {kb, kb+32, kb+64}), fp16 inputs, fp32 accum
    const int p = t & 7, kb = t >> 3;
    const bool has2 = (kb + 64 < KK);
    const int k0 = kb, k1 = kb + 32, k2 = has2 ? kb + 64 : kb;
    const int v0 = (k0 / 9) * 16 + p + k0 % 9;
    const int v1 = (k1 / 9) * 16 + p + k1 % 9;
    const int v2 = (k2 / 9) * 16 + p + k2 % 9;
    const int b0 = v0 << 7, m0 = v0 & 15;
    const int b1 = v1 << 7, m1 = v1 & 15;
    const int b2 = v2 << 7, m2 = v2 & 15;
    const int bq = p << 7;
    float s0 = 0.f, s1 = 0.f, s2 = 0.f;
#pragma unroll 4
    for (int ci = 0; ci < 16; ++ci) {
        const h8 q8 = *(const h8*)&Qsw[bq + ((ci ^ p) << 3)];
        const h8 kA = *(const h8*)&Ksw[b0 + ((ci ^ m0) << 3)];
        const h8 kB = *(const h8*)&Ksw[b1 + ((ci ^ m1) << 3)];
        const h8 kC = *(const h8*)&Ksw[b2 + ((ci ^ m2) << 3)];
        s0 = dot8(q8, kA, s0);
        s1 = dot8(q8, kB, s1);
        s2 = dot8(q8, kC, s2);
    }
    __syncthreads();   // B2: Ksw/Qsw dead, safe to overwrite with ftl

    // ---- restage ft (fp16) into ftl[row*132 + c], row = r*16+xx
#pragma unroll 2
    for (int e = t; e < 4608; e += 256) {           // 9 r x 128 c x 4 j
        const int j = e & 3, c = (e >> 2) & 127, r = e >> 9;
        const int gx0 = x0 - 4 + (j << 2);          // quad fully in or fully out
        const int gy = y + r - 4;
        float4 v = make_float4(0, 0, 0, 0);
        if ((unsigned)gy < 64u && (unsigned)gx0 < 64u)
            v = *(const float4*)&ft[(size_t)((nn * Cc + c) << 12) + (gy << 6) + gx0];
        const int base = ((r << 4) + (j << 2)) * 132 + c;
        ftl[base]       = (_Float16)v.x;
        ftl[base + 132] = (_Float16)v.y;
        ftl[base + 264] = (_Float16)v.z;
        ftl[base + 396] = (_Float16)v.w;
    }

    // ---- softmax in registers: reduce over lanes sharing p (bits 3..5 of lane id)
    float m = fmaxf(s0, s1);
    if (has2) m = fmaxf(m, s2);
#pragma unroll
    for (int off = 8; off <= 32; off <<= 1) m = fmaxf(m, __shfl_xor(m, off));
    if ((t & 56) == 0) redM[((t >> 6) << 3) + p] = m;   // one lane per (wave, p)
    __syncthreads();   // B3 (also covers ftl writes)
    float mm = fmaxf(fmaxf(redM[p], redM[8 + p]), fmaxf(redM[16 + p], redM[24 + p]));
    const float e0 = __expf(s0 - mm);
    const float e1 = __expf(s1 - mm);
    const float e2 = has2 ? __expf(s2 - mm) : 0.f;
    simb[k0 * 8 + p] = (_Float16)e0;
    simb[k1 * 8 + p] = (_Float16)e1;
    if (has2) simb[(kb + 64) * 8 + p] = (_Float16)e2;
    float s = e0 + e1 + e2;
#pragma unroll
    for (int off = 8; off <= 32; off <<= 1) s += __shfl_xor(s, off);
    if ((t & 56) == 0) redS[((t >> 6) << 3) + p] = s;
    __syncthreads();   // B4
    const float inv = 1.f / (redS[p] + redS[8 + p] + redS[16 + p] + redS[24 + p]);

    // ---- weighting: thread = (p, cq); 4 channels per thread, fp16 ftl, fp32 accum
    const int cq = t >> 3;
    float4 acc = make_float4(0, 0, 0, 0);
    for (int r = 0; r < 9; ++r) {
        const int rb = ((r << 4) + p) * 132 + (cq << 2);
        const int k9 = r * 9;
#pragma unroll
        for (int dx = 0; dx < 9; ++dx) {
            const float w = (float)simb[(k9 + dx) * 8 + p];  // 8-lane broadcast
            const h4 f = *(const h4*)&ftl[rb + dx * 132];
            acc.x += (float)f[0] * w;
            acc.y += (float)f[1] * w;
            acc.z += (float)f[2] * w;
            acc.w += (float)f[3] * w;
        }
    }
    const size_t ob = (size_t)((nn * Cc + (cq << 2)) << 12) + (y << 6) + x0 + p;
    out[ob]          = acc.x * inv;
    out[ob + HW]     = acc.y * inv;
    out[ob + 2*HW]   = acc.z * inv;
    out[ob + 3*HW]   = acc.w * inv;
}

extern "C" void kernel_launch(void* const* d_in, const int* in_sizes, int n_in,
                              void* d_out, int out_size, void* d_ws, size_t ws_size,
                              hipStream_t stream) {
    const float* ft = (const float*)d_in[0];
    const float* fk = (const float*)d_in[1];
    const float* Wm = (const float*)d_in[2];
    float* out = (float*)d_out;

    _Float16* wsh  = (_Float16*)d_ws;    // 4 MB: Qh(2MB) + Kh(2MB)
    _Float16* Qbuf = wsh;                // [p][c]  8192*128 halves
    _Float16* Kbuf = wsh + 1048576;      // [p][c]  8192*128 halves

    proj_kernel<<<512, 256, 0, stream>>>(ft, fk, Wm, Qbuf, Kbuf);
    sim_weight_kernel<<<1024, 256, 0, stream>>>(Qbuf, Kbuf, ft, out);
}

// Round 11
// 94.324 us; speedup vs baseline: 1.0589x; 1.0589x over previous
//
#include <hip/hip_runtime.h>
#include <hip/hip_bf16.h>

// ILA layer (fp32 I/O): key = W@ft, query = W@fk (1x1 conv, shared W),
// sim[p,k] = <query[p], key[neighbor_k(p)]> over 9x9 window (zero-padded keys),
// weight = softmax_k(sim)  (OOB entries participate with sim=0),
// out[c,p] = sum_k weight[k] * ft[c, neighbor_k(p)]  (zero-padded ft).
// n=2, c=128, h=w=64, L=9 (81 neighbors).
// K/Q/ft-staging intermediates are fp16 (absmax 0.031 vs 0.099 threshold, measured).

#define Hh 64
#define Ww 64
#define Cc 128
#define Nn 2
#define KK 81
#define HW (Hh * Ww)          // 4096
#define CHW (Cc * HW)         // 524288
#define P_TOT (Nn * HW)       // 8192

typedef _Float16 h8 __attribute__((ext_vector_type(8)));
typedef _Float16 h4 __attribute__((ext_vector_type(4)));
typedef _Float16 h2 __attribute__((ext_vector_type(2)));

__device__ __forceinline__ void fma4(float4& a, const float4 b, const float s) {
    a.x += b.x * s; a.y += b.y * s; a.z += b.z * s; a.w += b.w * s;
}

__device__ __forceinline__ float dot8(const h8 a, const h8 b, float acc) {
#if __has_builtin(__builtin_amdgcn_fdot2)
    h2 a0 = {a[0], a[1]}, b0 = {b[0], b[1]};
    h2 a1 = {a[2], a[3]}, b1 = {b[2], b[3]};
    h2 a2 = {a[4], a[5]}, b2 = {b[4], b[5]};
    h2 a3 = {a[6], a[7]}, b3 = {b[6], b[7]};
    acc = __builtin_amdgcn_fdot2(a0, b0, acc, false);
    acc = __builtin_amdgcn_fdot2(a1, b1, acc, false);
    acc = __builtin_amdgcn_fdot2(a2, b2, acc, false);
    acc = __builtin_amdgcn_fdot2(a3, b3, acc, false);
#else
#pragma unroll
    for (int i = 0; i < 8; ++i) acc += (float)a[i] * (float)b[i];
#endif
    return acc;
}

// ---------------- Kernel A: projection (K = W*ft, Q = W*fk), fp16 pixel-major out.
// R9-measured shape: 256 blocks x 256 thr; 32 px/block; tile = 4 px x 4 out x {K,Q}.
// Also emits fth = fp16 mirror of ft (coalesced b16 stores) so sim's restage
// reads half the bytes and does zero converts.
__global__ __launch_bounds__(256) void proj_kernel(const float* __restrict__ ft,
                                                   const float* __restrict__ fk,
                                                   const float* __restrict__ Wm,
                                                   _Float16* __restrict__ Qbuf,
                                                   _Float16* __restrict__ Kbuf,
                                                   _Float16* __restrict__ fth) {
    __shared__ __align__(16) float Wl[32 * 132];   // [ii][o] chunk of W^T
    __shared__ __align__(16) float xkl[128 * 36];  // [i][pl]
    __shared__ __align__(16) float xql[128 * 36];
    const int t = threadIdx.x;
    const int p0 = blockIdx.x * 32;       // 4096 % 32 == 0: never crosses n
    const int nn = p0 >> 12;
    const int gbase = nn * CHW + (p0 & 4095);

    for (int e = t; e < 128 * 32; e += 256) {       // stage x tiles (coalesced 128B runs)
        const int c = e >> 5, pl = e & 31;
        const float vk = ft[gbase + c * HW + pl];
        xkl[c * 36 + pl] = vk;
        xql[c * 36 + pl] = fk[gbase + c * HW + pl];
        fth[gbase + c * HW + pl] = (_Float16)vk;    // fp16 ft mirror, coalesced
    }

    const int po = t & 7;                 // 8 pixel groups x 4 px
    const int oo = t >> 3;                // 32 out groups x 4 out
    float4 accK[4], accQ[4];
#pragma unroll
    for (int i = 0; i < 4; ++i) { accK[i] = make_float4(0,0,0,0); accQ[i] = make_float4(0,0,0,0); }

    for (int ch = 0; ch < 4; ++ch) {
        for (int e = t; e < 128 * 32; e += 256) {   // Wl[ii][o] <- Wm[o][ch*32+ii]
            const int o = e >> 5, ii = e & 31;
            Wl[ii * 132 + o] = Wm[o * 128 + (ch << 5) + ii];
        }
        __syncthreads();
#pragma unroll 4
        for (int ii = 0; ii < 32; ++ii) {
            const int i = (ch << 5) + ii;
            const float4 w4 = *(const float4*)&Wl[ii * 132 + (oo << 2)];
            const float4 k4 = *(const float4*)&xkl[i * 36 + (po << 2)];
            const float4 q4 = *(const float4*)&xql[i * 36 + (po << 2)];
            fma4(accK[0], k4, w4.x); fma4(accK[1], k4, w4.y);
            fma4(accK[2], k4, w4.z); fma4(accK[3], k4, w4.w);
            fma4(accQ[0], q4, w4.x); fma4(accQ[1], q4, w4.y);
            fma4(accQ[2], q4, w4.z); fma4(accQ[3], q4, w4.w);
        }
        __syncthreads();
    }

    // register transpose -> px-major h4 stores (channels 4oo..4oo+3 per pixel)
    const int pbase = p0 + (po << 2);
    const float kr[4][4] = {
        {accK[0].x, accK[1].x, accK[2].x, accK[3].x},
        {accK[0].y, accK[1].y, accK[2].y, accK[3].y},
        {accK[0].z, accK[1].z, accK[2].z, accK[3].z},
        {accK[0].w, accK[1].w, accK[2].w, accK[3].w}};
    const float qr[4][4] = {
        {accQ[0].x, accQ[1].x, accQ[2].x, accQ[3].x},
        {accQ[0].y, accQ[1].y, accQ[2].y, accQ[3].y},
        {accQ[0].z, accQ[1].z, accQ[2].z, accQ[3].z},
        {accQ[0].w, accQ[1].w, accQ[2].w, accQ[3].w}};
#pragma unroll
    for (int pp = 0; pp < 4; ++pp) {
        const size_t base = (size_t)(pbase + pp) * 128 + (oo << 2);
        h4 kv, qv;
#pragma unroll
        for (int j = 0; j < 4; ++j) { kv[j] = (_Float16)kr[pp][j]; qv[j] = (_Float16)qr[pp][j]; }
        *(h4*)&Kbuf[base] = kv;
        *(h4*)&Qbuf[base] = qv;
    }
}

// ---------------- Kernel B (fused): sim + softmax + weighting. Block = 8-px row strip.
// K/Q/ft all arrive fp16; LDS ~40 KB => 4 blocks/CU (16 waves/CU).
__global__ __launch_bounds__(256, 4) void sim_weight_kernel(const _Float16* __restrict__ Qbuf,
                                                            const _Float16* __restrict__ Kbuf,
                                                            const _Float16* __restrict__ fth,
                                                            float* __restrict__ out) {
    __shared__ __align__(16) unsigned char smem[40464];
    _Float16* Ksw  = (_Float16*)smem;             // 18432 halves [0, 36864)
    _Float16* Qsw  = (_Float16*)(smem + 36864);   // 1024 halves  [36864, 38912)
    _Float16* ftl  = (_Float16*)smem;             // 19008 halves [0, 38016) — aliases Ksw/Qsw after B2
    _Float16* simb = (_Float16*)(smem + 38912);   // 648 halves   [38912, 40208)
    float*    redM = (float*)(smem + 40208);      // 32 floats
    float*    redS = (float*)(smem + 40336);      // 32 floats

    const int t  = threadIdx.x;
    const int b  = blockIdx.x;
    const int x0 = (b & 7) << 3;
    const int y  = (b >> 3) & 63;
    const int nn = b >> 9;
    const int pg0 = (nn << 12) + (y << 6) + x0;

    // ---- stage K: zero-padded 9x16 window, straight h8 copies, XOR-swizzled slots
#pragma unroll 3
    for (int e = t; e < 144 * 16; e += 256) {     // 2304 16B chunks
        const int v = e >> 4, ci = e & 15;
        const int gx = x0 + (v & 15) - 4;
        const int gy = y + (v >> 4) - 4;
        h8 val = {0, 0, 0, 0, 0, 0, 0, 0};
        if ((unsigned)gx < 64u && (unsigned)gy < 64u)
            val = *(const h8*)&Kbuf[(size_t)((nn << 12) + (gy << 6) + gx) * 128 + (ci << 3)];
        *(h8*)&Ksw[(v << 7) + ((ci ^ (v & 15)) << 3)] = val;
    }
    if (t < 128) {   // stage Q: 8 vectors x 16 chunks
        const int v = t >> 4, ci = t & 15;
        *(h8*)&Qsw[(v << 7) + ((ci ^ v) << 3)] =
            *(const h8*)&Qbuf[(size_t)(pg0 + v) * 128 + (ci << 3)];
    }
    __syncthreads();   // B1

    // ---- dots: thread -> (pixel p, k in {kb, kb+32, kb+64}), fp16 inputs, fp32 accum
    const int p = t & 7, kb = t >> 3;
    const bool has2 = (kb + 64 < KK);
    const int k0 = kb, k1 = kb + 32, k2 = has2 ? kb + 64 : kb;
    const int v0 = (k0 / 9) * 16 + p + k0 % 9;
    const int v1 = (k1 / 9) * 16 + p + k1 % 9;
    const int v2 = (k2 / 9) * 16 + p + k2 % 9;
    const int b0 = v0 << 7, m0 = v0 & 15;
    const int b1 = v1 << 7, m1 = v1 & 15;
    const int b2 = v2 << 7, m2 = v2 & 15;
    const int bq = p << 7;
    float s0 = 0.f, s1 = 0.f, s2 = 0.f;
#pragma unroll 4
    for (int ci = 0; ci < 16; ++ci) {
        const h8 q8 = *(const h8*)&Qsw[bq + ((ci ^ p) << 3)];
        const h8 kA = *(const h8*)&Ksw[b0 + ((ci ^ m0) << 3)];
        const h8 kB = *(const h8*)&Ksw[b1 + ((ci ^ m1) << 3)];
        const h8 kC = *(const h8*)&Ksw[b2 + ((ci ^ m2) << 3)];
        s0 = dot8(q8, kA, s0);
        s1 = dot8(q8, kB, s1);
        s2 = dot8(q8, kC, s2);
    }
    __syncthreads();   // B2: Ksw/Qsw dead, safe to overwrite with ftl

    // ---- restage ft (already fp16 via fth) into ftl[row*132 + c], row = r*16+xx
#pragma unroll 2
    for (int e = t; e < 4608; e += 256) {           // 9 r x 128 c x 4 j
        const int j = e & 3, c = (e >> 2) & 127, r = e >> 9;
        const int gx0 = x0 - 4 + (j << 2);          // quad fully in or fully out
        const int gy = y + r - 4;
        h4 v = {0, 0, 0, 0};
        if ((unsigned)gy < 64u && (unsigned)gx0 < 64u)
            v = *(const h4*)&fth[(size_t)((nn * Cc + c) << 12) + (gy << 6) + gx0];
        const int base = ((r << 4) + (j << 2)) * 132 + c;
        ftl[base]       = v[0];
        ftl[base + 132] = v[1];
        ftl[base + 264] = v[2];
        ftl[base + 396] = v[3];
    }

    // ---- softmax in registers: reduce over lanes sharing p (bits 3..5 of lane id)
    float m = fmaxf(s0, s1);
    if (has2) m = fmaxf(m, s2);
#pragma unroll
    for (int off = 8; off <= 32; off <<= 1) m = fmaxf(m, __shfl_xor(m, off));
    if ((t & 56) == 0) redM[((t >> 6) << 3) + p] = m;   // one lane per (wave, p)
    __syncthreads();   // B3 (also covers ftl writes)
    float mm = fmaxf(fmaxf(redM[p], redM[8 + p]), fmaxf(redM[16 + p], redM[24 + p]));
    const float e0 = __expf(s0 - mm);
    const float e1 = __expf(s1 - mm);
    const float e2 = has2 ? __expf(s2 - mm) : 0.f;
    simb[k0 * 8 + p] = (_Float16)e0;
    simb[k1 * 8 + p] = (_Float16)e1;
    if (has2) simb[(kb + 64) * 8 + p] = (_Float16)e2;
    float s = e0 + e1 + e2;
#pragma unroll
    for (int off = 8; off <= 32; off <<= 1) s += __shfl_xor(s, off);
    if ((t & 56) == 0) redS[((t >> 6) << 3) + p] = s;
    __syncthreads();   // B4
    const float inv = 1.f / (redS[p] + redS[8 + p] + redS[16 + p] + redS[24 + p]);

    // ---- weighting: thread = (p, cq); 4 channels per thread, fp16 ftl, fp32 accum
    const int cq = t >> 3;
    float4 acc = make_float4(0, 0, 0, 0);
    for (int r = 0; r < 9; ++r) {
        const int rb = ((r << 4) + p) * 132 + (cq << 2);
        const int k9 = r * 9;
#pragma unroll
        for (int dx = 0; dx < 9; ++dx) {
            const float w = (float)simb[(k9 + dx) * 8 + p];  // 8-lane broadcast
            const h4 f = *(const h4*)&ftl[rb + dx * 132];
            acc.x += (float)f[0] * w;
            acc.y += (float)f[1] * w;
            acc.z += (float)f[2] * w;
            acc.w += (float)f[3] * w;
        }
    }
    const size_t ob = (size_t)((nn * Cc + (cq << 2)) << 12) + (y << 6) + x0 + p;
    out[ob]          = acc.x * inv;
    out[ob + HW]     = acc.y * inv;
    out[ob + 2*HW]   = acc.z * inv;
    out[ob + 3*HW]   = acc.w * inv;
}

extern "C" void kernel_launch(void* const* d_in, const int* in_sizes, int n_in,
                              void* d_out, int out_size, void* d_ws, size_t ws_size,
                              hipStream_t stream) {
    const float* ft = (const float*)d_in[0];
    const float* fk = (const float*)d_in[1];
    const float* Wm = (const float*)d_in[2];
    float* out = (float*)d_out;

    _Float16* wsh  = (_Float16*)d_ws;    // 6 MB: Qh(2MB) + Kh(2MB) + fth(2MB)
    _Float16* Qbuf = wsh;                // [p][c]  8192*128 halves
    _Float16* Kbuf = wsh + 1048576;      // [p][c]  8192*128 halves
    _Float16* fth  = wsh + 2097152;      // fp16 mirror of ft, same layout

    proj_kernel<<<256, 256, 0, stream>>>(ft, fk, Wm, Qbuf, Kbuf, fth);
    sim_weight_kernel<<<1024, 256, 0, stream>>>(Qbuf, Kbuf, fth, out);
}

// Round 12
// 89.297 us; speedup vs baseline: 1.1186x; 1.0563x over previous
//
#include <hip/hip_runtime.h>
#include <hip/hip_bf16.h>

// ILA layer (fp32 I/O): key = W@ft, query = W@fk (1x1 conv, shared W),
// sim[p,k] = <query[p], key[neighbor_k(p)]> over 9x9 window (zero-padded keys),
// weight = softmax_k(sim)  (OOB entries participate with sim=0),
// out[c,p] = sum_k weight[k] * ft[c, neighbor_k(p)]  (zero-padded ft).
// n=2, c=128, h=w=64, L=9 (81 neighbors).
// K/Q/ft-staging intermediates fp16 (absmax 0.031 vs 0.099 threshold, measured).
// fth is PIXEL-MAJOR [p][c] so sim's ftl restage is straight h8 copies (no transpose).

#define Hh 64
#define Ww 64
#define Cc 128
#define Nn 2
#define KK 81
#define HW (Hh * Ww)          // 4096
#define CHW (Cc * HW)         // 524288
#define P_TOT (Nn * HW)       // 8192

typedef _Float16 h8 __attribute__((ext_vector_type(8)));
typedef _Float16 h4 __attribute__((ext_vector_type(4)));
typedef _Float16 h2 __attribute__((ext_vector_type(2)));

__device__ __forceinline__ void fma4(float4& a, const float4 b, const float s) {
    a.x += b.x * s; a.y += b.y * s; a.z += b.z * s; a.w += b.w * s;
}

__device__ __forceinline__ float dot8(const h8 a, const h8 b, float acc) {
#if __has_builtin(__builtin_amdgcn_fdot2)
    h2 a0 = {a[0], a[1]}, b0 = {b[0], b[1]};
    h2 a1 = {a[2], a[3]}, b1 = {b[2], b[3]};
    h2 a2 = {a[4], a[5]}, b2 = {b[4], b[5]};
    h2 a3 = {a[6], a[7]}, b3 = {b[6], b[7]};
    acc = __builtin_amdgcn_fdot2(a0, b0, acc, false);
    acc = __builtin_amdgcn_fdot2(a1, b1, acc, false);
    acc = __builtin_amdgcn_fdot2(a2, b2, acc, false);
    acc = __builtin_amdgcn_fdot2(a3, b3, acc, false);
#else
#pragma unroll
    for (int i = 0; i < 8; ++i) acc += (float)a[i] * (float)b[i];
#endif
    return acc;
}

// ---------------- Kernel A: projection (K = W*ft, Q = W*fk), fp16 pixel-major out.
// R9/R11-measured shape: 256 blocks x 256 thr; 32 px/block; tile = 4 px x 4 out.
// Also emits fth = fp16 ft, PIXEL-MAJOR [p][c], via LDS transpose of the x-tile.
__global__ __launch_bounds__(256) void proj_kernel(const float* __restrict__ ft,
                                                   const float* __restrict__ fk,
                                                   const float* __restrict__ Wm,
                                                   _Float16* __restrict__ Qbuf,
                                                   _Float16* __restrict__ Kbuf,
                                                   _Float16* __restrict__ fth) {
    __shared__ __align__(16) float Wl[32 * 132];   // [ii][o] chunk of W^T
    __shared__ __align__(16) float xkl[128 * 36];  // [i][pl]
    __shared__ __align__(16) float xql[128 * 36];
    const int t = threadIdx.x;
    const int p0 = blockIdx.x * 32;       // 4096 % 32 == 0: never crosses n
    const int nn = p0 >> 12;
    const int gbase = nn * CHW + (p0 & 4095);

    for (int e = t; e < 128 * 32; e += 256) {       // stage x tiles (coalesced 128B runs)
        const int c = e >> 5, pl = e & 31;
        xkl[c * 36 + pl] = ft[gbase + c * HW + pl];
        xql[c * 36 + pl] = fk[gbase + c * HW + pl];
    }

    const int po = t & 7;                 // 8 pixel groups x 4 px
    const int oo = t >> 3;                // 32 out groups x 4 out
    float4 accK[4], accQ[4];
#pragma unroll
    for (int i = 0; i < 4; ++i) { accK[i] = make_float4(0,0,0,0); accQ[i] = make_float4(0,0,0,0); }

    for (int ch = 0; ch < 4; ++ch) {
        for (int e = t; e < 128 * 32; e += 256) {   // Wl[ii][o] <- Wm[o][ch*32+ii]
            const int o = e >> 5, ii = e & 31;
            Wl[ii * 132 + o] = Wm[o * 128 + (ch << 5) + ii];
        }
        __syncthreads();
#pragma unroll 4
        for (int ii = 0; ii < 32; ++ii) {
            const int i = (ch << 5) + ii;
            const float4 w4 = *(const float4*)&Wl[ii * 132 + (oo << 2)];
            const float4 k4 = *(const float4*)&xkl[i * 36 + (po << 2)];
            const float4 q4 = *(const float4*)&xql[i * 36 + (po << 2)];
            fma4(accK[0], k4, w4.x); fma4(accK[1], k4, w4.y);
            fma4(accK[2], k4, w4.z); fma4(accK[3], k4, w4.w);
            fma4(accQ[0], q4, w4.x); fma4(accQ[1], q4, w4.y);
            fma4(accQ[2], q4, w4.z); fma4(accQ[3], q4, w4.w);
        }
        __syncthreads();
    }

    // register transpose -> px-major h4 stores (channels 4oo..4oo+3 per pixel)
    const int pbase = p0 + (po << 2);
    const float kr[4][4] = {
        {accK[0].x, accK[1].x, accK[2].x, accK[3].x},
        {accK[0].y, accK[1].y, accK[2].y, accK[3].y},
        {accK[0].z, accK[1].z, accK[2].z, accK[3].z},
        {accK[0].w, accK[1].w, accK[2].w, accK[3].w}};
    const float qr[4][4] = {
        {accQ[0].x, accQ[1].x, accQ[2].x, accQ[3].x},
        {accQ[0].y, accQ[1].y, accQ[2].y, accQ[3].y},
        {accQ[0].z, accQ[1].z, accQ[2].z, accQ[3].z},
        {accQ[0].w, accQ[1].w, accQ[2].w, accQ[3].w}};
#pragma unroll
    for (int pp = 0; pp < 4; ++pp) {
        const size_t base = (size_t)(pbase + pp) * 128 + (oo << 2);
        h4 kv, qv;
#pragma unroll
        for (int j = 0; j < 4; ++j) { kv[j] = (_Float16)kr[pp][j]; qv[j] = (_Float16)qr[pp][j]; }
        *(h4*)&Kbuf[base] = kv;
        *(h4*)&Qbuf[base] = qv;
    }

    // fth pixel-major: thread (po,oo) writes 4 px x 4 ch from the (still-valid) xkl tile
#pragma unroll
    for (int pp = 0; pp < 4; ++pp) {
        h4 v;
#pragma unroll
        for (int j = 0; j < 4; ++j)
            v[j] = (_Float16)xkl[((oo << 2) + j) * 36 + (po << 2) + pp];
        *(h4*)&fth[(size_t)(pbase + pp) * 128 + (oo << 2)] = v;
    }
}

// ---------------- Kernel B (fused): sim + softmax + weighting. Block = 8-px row strip.
// K/Q/fth all fp16 pixel-major; ftl restage = straight h8 copies (no transpose).
// LDS 40720 B => 4 blocks/CU (16 waves/CU).
__global__ __launch_bounds__(256, 4) void sim_weight_kernel(const _Float16* __restrict__ Qbuf,
                                                            const _Float16* __restrict__ Kbuf,
                                                            const _Float16* __restrict__ fth,
                                                            float* __restrict__ out) {
    __shared__ __align__(16) unsigned char smem[40720];
    _Float16* Ksw  = (_Float16*)smem;             // 18432 halves [0, 36864)
    _Float16* Qsw  = (_Float16*)(smem + 36864);   // 1024 halves  [36864, 38912)
    _Float16* ftl  = (_Float16*)smem;             // [row][c] stride 136: 144*136=19584 halves [0,39168)
    _Float16* simb = (_Float16*)(smem + 39168);   // 648 halves   [39168, 40464)
    float*    redM = (float*)(smem + 40464);      // 32 floats
    float*    redS = (float*)(smem + 40592);      // 32 floats

    const int t  = threadIdx.x;
    const int b  = blockIdx.x;
    const int x0 = (b & 7) << 3;
    const int y  = (b >> 3) & 63;
    const int nn = b >> 9;
    const int pg0 = (nn << 12) + (y << 6) + x0;

    // ---- stage K: zero-padded 9x16 window, straight h8 copies, XOR-swizzled slots
#pragma unroll 3
    for (int e = t; e < 144 * 16; e += 256) {     // 2304 16B chunks
        const int v = e >> 4, ci = e & 15;
        const int gx = x0 + (v & 15) - 4;
        const int gy = y + (v >> 4) - 4;
        h8 val = {0, 0, 0, 0, 0, 0, 0, 0};
        if ((unsigned)gx < 64u && (unsigned)gy < 64u)
            val = *(const h8*)&Kbuf[(size_t)((nn << 12) + (gy << 6) + gx) * 128 + (ci << 3)];
        *(h8*)&Ksw[(v << 7) + ((ci ^ (v & 15)) << 3)] = val;
    }
    if (t < 128) {   // stage Q: 8 vectors x 16 chunks
        const int v = t >> 4, ci = t & 15;
        *(h8*)&Qsw[(v << 7) + ((ci ^ v) << 3)] =
            *(const h8*)&Qbuf[(size_t)(pg0 + v) * 128 + (ci << 3)];
    }
    __syncthreads();   // B1

    // ---- dots: thread -> (pixel p, k in {kb, kb+32, kb+64}), fp16 inputs, fp32 accum
    const int p = t & 7, kb = t >> 3;
    const bool has2 = (kb + 64 < KK);
    const int k0 = kb, k1 = kb + 32, k2 = has2 ? kb + 64 : kb;
    const int v0 = (k0 / 9) * 16 + p + k0 % 9;
    const int v1 = (k1 / 9) * 16 + p + k1 % 9;
    const int v2 = (k2 / 9) * 16 + p + k2 % 9;
    const int b0 = v0 << 7, m0 = v0 & 15;
    const int b1 = v1 << 7, m1 = v1 & 15;
    const int b2 = v2 << 7, m2 = v2 & 15;
    const int bq = p << 7;
    float s0 = 0.f, s1 = 0.f, s2 = 0.f;
#pragma unroll 4
    for (int ci = 0; ci < 16; ++ci) {
        const h8 q8 = *(const h8*)&Qsw[bq + ((ci ^ p) << 3)];
        const h8 kA = *(const h8*)&Ksw[b0 + ((ci ^ m0) << 3)];
        const h8 kB = *(const h8*)&Ksw[b1 + ((ci ^ m1) << 3)];
        const h8 kC = *(const h8*)&Ksw[b2 + ((ci ^ m2) << 3)];
        s0 = dot8(q8, kA, s0);
        s1 = dot8(q8, kB, s1);
        s2 = dot8(q8, kC, s2);
    }
    __syncthreads();   // B2: Ksw/Qsw dead, safe to overwrite with ftl

    // ---- restage ft: straight h8 copies fth[pixel] -> ftl[row][c], stride 136
    // (writes: 8 bank-words/bank balanced; weighting h4 reads: 4/bank balanced)
#pragma unroll 3
    for (int e = t; e < 144 * 16; e += 256) {     // 2304 16B chunks
        const int v = e >> 4, ci = e & 15;
        const int gx = x0 + (v & 15) - 4;
        const int gy = y + (v >> 4) - 4;
        h8 val = {0, 0, 0, 0, 0, 0, 0, 0};
        if ((unsigned)gx < 64u && (unsigned)gy < 64u)
            val = *(const h8*)&fth[(size_t)((nn << 12) + (gy << 6) + gx) * 128 + (ci << 3)];
        *(h8*)&ftl[v * 136 + (ci << 3)] = val;
    }

    // ---- softmax in registers: reduce over lanes sharing p (bits 3..5 of lane id)
    float m = fmaxf(s0, s1);
    if (has2) m = fmaxf(m, s2);
#pragma unroll
    for (int off = 8; off <= 32; off <<= 1) m = fmaxf(m, __shfl_xor(m, off));
    if ((t & 56) == 0) redM[((t >> 6) << 3) + p] = m;   // one lane per (wave, p)
    __syncthreads();   // B3 (also covers ftl writes)
    float mm = fmaxf(fmaxf(redM[p], redM[8 + p]), fmaxf(redM[16 + p], redM[24 + p]));
    const float e0 = __expf(s0 - mm);
    const float e1 = __expf(s1 - mm);
    const float e2 = has2 ? __expf(s2 - mm) : 0.f;
    simb[k0 * 8 + p] = (_Float16)e0;
    simb[k1 * 8 + p] = (_Float16)e1;
    if (has2) simb[(kb + 64) * 8 + p] = (_Float16)e2;
    float s = e0 + e1 + e2;
#pragma unroll
    for (int off = 8; off <= 32; off <<= 1) s += __shfl_xor(s, off);
    if ((t & 56) == 0) redS[((t >> 6) << 3) + p] = s;
    __syncthreads();   // B4
    const float inv = 1.f / (redS[p] + redS[8 + p] + redS[16 + p] + redS[24 + p]);

    // ---- weighting: thread = (p, cq); 4 channels per thread, fp16 ftl, fp32 accum
    const int cq = t >> 3;
    float4 acc = make_float4(0, 0, 0, 0);
    for (int r = 0; r < 9; ++r) {
        const int rb = ((r << 4) + p) * 136 + (cq << 2);
        const int k9 = r * 9;
#pragma unroll
        for (int dx = 0; dx < 9; ++dx) {
            const float w = (float)simb[(k9 + dx) * 8 + p];  // 8-lane broadcast
            const h4 f = *(const h4*)&ftl[rb + dx * 136];
            acc.x += (float)f[0] * w;
            acc.y += (float)f[1] * w;
            acc.z += (float)f[2] * w;
            acc.w += (float)f[3] * w;
        }
    }
    const size_t ob = (size_t)((nn * Cc + (cq << 2)) << 12) + (y << 6) + x0 + p;
    out[ob]          = acc.x * inv;
    out[ob + HW]     = acc.y * inv;
    out[ob + 2*HW]   = acc.z * inv;
    out[ob + 3*HW]   = acc.w * inv;
}

extern "C" void kernel_launch(void* const* d_in, const int* in_sizes, int n_in,
                              void* d_out, int out_size, void* d_ws, size_t ws_size,
                              hipStream_t stream) {
    const float* ft = (const float*)d_in[0];
    const float* fk = (const float*)d_in[1];
    const float* Wm = (const float*)d_in[2];
    float* out = (float*)d_out;

    _Float16* wsh  = (_Float16*)d_ws;    // 6 MB: Qh(2MB) + Kh(2MB) + fth(2MB)
    _Float16* Qbuf = wsh;                // [p][c]  8192*128 halves
    _Float16* Kbuf = wsh + 1048576;      // [p][c]  8192*128 halves
    _Float16* fth  = wsh + 2097152;      // fp16 ft, PIXEL-MAJOR [p][c]

    proj_kernel<<<256, 256, 0, stream>>>(ft, fk, Wm, Qbuf, Kbuf, fth);
    sim_weight_kernel<<<1024, 256, 0, stream>>>(Qbuf, Kbuf, fth, out);
}

// Round 13
// 80.518 us; speedup vs baseline: 1.2405x; 1.1090x over previous
//
#include <hip/hip_runtime.h>
#include <hip/hip_bf16.h>

// ILA layer (fp32 I/O): key = W@ft, query = W@fk (1x1 conv, shared W),
// sim[p,k] = <query[p], key[neighbor_k(p)]> over 9x9 window (zero-padded keys),
// weight = softmax_k(sim)  (OOB entries participate with sim=0),
// out[c,p] = sum_k weight[k] * ft[c, neighbor_k(p)]  (zero-padded ft).
// n=2, c=128, h=w=64, L=9 (81 neighbors).
// K/Q/ft intermediates fp16. proj is now an MFMA GEMM (v_mfma_f32_16x16x32_f16,
// fp32 accumulate): A = x pixel-major, B = W row-major ([k][n] = Wm[n][k] directly).

#define Hh 64
#define Ww 64
#define Cc 128
#define Nn 2
#define KK 81
#define HW (Hh * Ww)          // 4096
#define CHW (Cc * HW)         // 524288
#define P_TOT (Nn * HW)       // 8192

typedef _Float16 h8 __attribute__((ext_vector_type(8)));
typedef _Float16 h4 __attribute__((ext_vector_type(4)));
typedef _Float16 h2 __attribute__((ext_vector_type(2)));
typedef float f4v __attribute__((ext_vector_type(4)));

__device__ __forceinline__ float dot8(const h8 a, const h8 b, float acc) {
#if __has_builtin(__builtin_amdgcn_fdot2)
    h2 a0 = {a[0], a[1]}, b0 = {b[0], b[1]};
    h2 a1 = {a[2], a[3]}, b1 = {b[2], b[3]};
    h2 a2 = {a[4], a[5]}, b2 = {b[4], b[5]};
    h2 a3 = {a[6], a[7]}, b3 = {b[6], b[7]};
    acc = __builtin_amdgcn_fdot2(a0, b0, acc, false);
    acc = __builtin_amdgcn_fdot2(a1, b1, acc, false);
    acc = __builtin_amdgcn_fdot2(a2, b2, acc, false);
    acc = __builtin_amdgcn_fdot2(a3, b3, acc, false);
#else
#pragma unroll
    for (int i = 0; i < 8; ++i) acc += (float)a[i] * (float)b[i];
#endif
    return acc;
}

// ---------------- Kernel A: projection via MFMA. 256 blocks x 256 thr, 32 px/block.
// Wave w: tensor = w>>1 (K or Q), m-tile = w&1 (16 px). 8 n-tiles x 4 K-chunks.
// LDS pads of 136 halves put all h8 frag reads at the 8-words/bank floor.
__global__ __launch_bounds__(256) void proj_kernel(const float* __restrict__ ft,
                                                   const float* __restrict__ fk,
                                                   const float* __restrict__ Wm,
                                                   _Float16* __restrict__ Qbuf,
                                                   _Float16* __restrict__ Kbuf,
                                                   _Float16* __restrict__ fth) {
    __shared__ __align__(16) _Float16 Wth[128 * 136];  // [o][i] fp16 (== B[k][n] view)
    __shared__ __align__(16) _Float16 xkh[32 * 136];   // [px][c] fp16
    __shared__ __align__(16) _Float16 xqh[32 * 136];
    const int t = threadIdx.x;
    const int p0 = blockIdx.x * 32;       // 4096 % 32 == 0: never crosses n
    const int nn = p0 >> 12;
    const int gbase = nn * CHW + (p0 & 4095);

    // stage W -> fp16, no transpose (Wth[n][k] = Wm[n][k])
#pragma unroll 4
    for (int e = t; e < 4096; e += 256) {             // 4096 float4 chunks
        const int n = e >> 5, ch = e & 31;
        const float4 v = *(const float4*)&Wm[n * 128 + (ch << 2)];
        h4 hv; hv[0] = (_Float16)v.x; hv[1] = (_Float16)v.y;
               hv[2] = (_Float16)v.z; hv[3] = (_Float16)v.w;
        *(h4*)&Wth[n * 136 + (ch << 2)] = hv;
    }
    // stage x -> fp16 pixel-major (transpose via scalar b16 writes)
#pragma unroll 4
    for (int e = t; e < 1024; e += 256) {             // 128 c x 8 chunks of 4 px
        const int c = e >> 3, pc = e & 7;
        const float4 vk = *(const float4*)&ft[gbase + c * HW + (pc << 2)];
        const float4 vq = *(const float4*)&fk[gbase + c * HW + (pc << 2)];
        const int px = pc << 2;
        xkh[(px    ) * 136 + c] = (_Float16)vk.x;
        xkh[(px + 1) * 136 + c] = (_Float16)vk.y;
        xkh[(px + 2) * 136 + c] = (_Float16)vk.z;
        xkh[(px + 3) * 136 + c] = (_Float16)vk.w;
        xqh[(px    ) * 136 + c] = (_Float16)vq.x;
        xqh[(px + 1) * 136 + c] = (_Float16)vq.y;
        xqh[(px + 2) * 136 + c] = (_Float16)vq.z;
        xqh[(px + 3) * 136 + c] = (_Float16)vq.w;
    }
    __syncthreads();

    // fth: coalesced h8 copies from the staged pixel-major ft tile
#pragma unroll
    for (int e = t; e < 512; e += 256) {              // 32 px x 16 h8 chunks
        const int px = e >> 4, cq = e & 15;
        *(h8*)&fth[(size_t)(p0 + px) * 128 + (cq << 3)] =
            *(const h8*)&xkh[px * 136 + (cq << 3)];
    }

    // MFMA compute. A-frag: A[m=lane&15][k=quad*8+j]; B-frag: B[k=quad*8+j][n=lane&15];
    // D: row(m)=quad*4+reg, col(n)=lane&15  [m89/m120-verified layouts]
    const int lane = t & 63, wv = t >> 6;
    const int quad = lane >> 4, l15 = lane & 15;
    const _Float16* xs = (wv >> 1) ? xqh : xkh;
    _Float16* dst = (wv >> 1) ? Qbuf : Kbuf;
    const int mt = wv & 1;
    const int abase = (mt * 16 + l15) * 136 + (quad << 3);
    const h8 a0 = *(const h8*)&xs[abase];
    const h8 a1 = *(const h8*)&xs[abase + 32];
    const h8 a2 = *(const h8*)&xs[abase + 64];
    const h8 a3 = *(const h8*)&xs[abase + 96];
#pragma unroll
    for (int nt = 0; nt < 8; ++nt) {
        const int bbase = (nt * 16 + l15) * 136 + (quad << 3);
        const h8 b0 = *(const h8*)&Wth[bbase];
        const h8 b1 = *(const h8*)&Wth[bbase + 32];
        const h8 b2 = *(const h8*)&Wth[bbase + 64];
        const h8 b3 = *(const h8*)&Wth[bbase + 96];
        f4v acc = {0.f, 0.f, 0.f, 0.f};
        acc = __builtin_amdgcn_mfma_f32_16x16x32_f16(a0, b0, acc, 0, 0, 0);
        acc = __builtin_amdgcn_mfma_f32_16x16x32_f16(a1, b1, acc, 0, 0, 0);
        acc = __builtin_amdgcn_mfma_f32_16x16x32_f16(a2, b2, acc, 0, 0, 0);
        acc = __builtin_amdgcn_mfma_f32_16x16x32_f16(a3, b3, acc, 0, 0, 0);
        const int col = nt * 16 + l15;
        const size_t rb = (size_t)(p0 + mt * 16 + (quad << 2)) * 128 + col;
#pragma unroll
        for (int r = 0; r < 4; ++r)
            dst[rb + (size_t)r * 128] = (_Float16)acc[r];
    }
}

// ---------------- Kernel B (fused): sim + softmax + weighting. Block = 8-px row strip.
// (R12-measured version, unchanged.)
__global__ __launch_bounds__(256, 4) void sim_weight_kernel(const _Float16* __restrict__ Qbuf,
                                                            const _Float16* __restrict__ Kbuf,
                                                            const _Float16* __restrict__ fth,
                                                            float* __restrict__ out) {
    __shared__ __align__(16) unsigned char smem[40720];
    _Float16* Ksw  = (_Float16*)smem;             // 18432 halves [0, 36864)
    _Float16* Qsw  = (_Float16*)(smem + 36864);   // 1024 halves  [36864, 38912)
    _Float16* ftl  = (_Float16*)smem;             // [row][c] stride 136: 19584 halves [0,39168)
    _Float16* simb = (_Float16*)(smem + 39168);   // 648 halves   [39168, 40464)
    float*    redM = (float*)(smem + 40464);      // 32 floats
    float*    redS = (float*)(smem + 40592);      // 32 floats

    const int t  = threadIdx.x;
    const int b  = blockIdx.x;
    const int x0 = (b & 7) << 3;
    const int y  = (b >> 3) & 63;
    const int nn = b >> 9;
    const int pg0 = (nn << 12) + (y << 6) + x0;

    // ---- stage K: zero-padded 9x16 window, straight h8 copies, XOR-swizzled slots
#pragma unroll 3
    for (int e = t; e < 144 * 16; e += 256) {     // 2304 16B chunks
        const int v = e >> 4, ci = e & 15;
        const int gx = x0 + (v & 15) - 4;
        const int gy = y + (v >> 4) - 4;
        h8 val = {0, 0, 0, 0, 0, 0, 0, 0};
        if ((unsigned)gx < 64u && (unsigned)gy < 64u)
            val = *(const h8*)&Kbuf[(size_t)((nn << 12) + (gy << 6) + gx) * 128 + (ci << 3)];
        *(h8*)&Ksw[(v << 7) + ((ci ^ (v & 15)) << 3)] = val;
    }
    if (t < 128) {   // stage Q: 8 vectors x 16 chunks
        const int v = t >> 4, ci = t & 15;
        *(h8*)&Qsw[(v << 7) + ((ci ^ v) << 3)] =
            *(const h8*)&Qbuf[(size_t)(pg0 + v) * 128 + (ci << 3)];
    }
    __syncthreads();   // B1

    // ---- dots: thread -> (pixel p, k in {kb, kb+32, kb+64}), fp16 inputs, fp32 accum
    const int p = t & 7, kb = t >> 3;
    const bool has2 = (kb + 64 < KK);
    const int k0 = kb, k1 = kb + 32, k2 = has2 ? kb + 64 : kb;
    const int v0 = (k0 / 9) * 16 + p + k0 % 9;
    const int v1 = (k1 / 9) * 16 + p + k1 % 9;
    const int v2 = (k2 / 9) * 16 + p + k2 % 9;
    const int b0 = v0 << 7, m0 = v0 & 15;
    const int b1 = v1 << 7, m1 = v1 & 15;
    const int b2 = v2 << 7, m2 = v2 & 15;
    const int bq = p << 7;
    float s0 = 0.f, s1 = 0.f, s2 = 0.f;
#pragma unroll 4
    for (int ci = 0; ci < 16; ++ci) {
        const h8 q8 = *(const h8*)&Qsw[bq + ((ci ^ p) << 3)];
        const h8 kA = *(const h8*)&Ksw[b0 + ((ci ^ m0) << 3)];
        const h8 kB = *(const h8*)&Ksw[b1 + ((ci ^ m1) << 3)];
        const h8 kC = *(const h8*)&Ksw[b2 + ((ci ^ m2) << 3)];
        s0 = dot8(q8, kA, s0);
        s1 = dot8(q8, kB, s1);
        s2 = dot8(q8, kC, s2);
    }
    __syncthreads();   // B2: Ksw/Qsw dead, safe to overwrite with ftl

    // ---- restage ft: straight h8 copies fth[pixel] -> ftl[row][c], stride 136
#pragma unroll 3
    for (int e = t; e < 144 * 16; e += 256) {     // 2304 16B chunks
        const int v = e >> 4, ci = e & 15;
        const int gx = x0 + (v & 15) - 4;
        const int gy = y + (v >> 4) - 4;
        h8 val = {0, 0, 0, 0, 0, 0, 0, 0};
        if ((unsigned)gx < 64u && (unsigned)gy < 64u)
            val = *(const h8*)&fth[(size_t)((nn << 12) + (gy << 6) + gx) * 128 + (ci << 3)];
        *(h8*)&ftl[v * 136 + (ci << 3)] = val;
    }

    // ---- softmax in registers: reduce over lanes sharing p (bits 3..5 of lane id)
    float m = fmaxf(s0, s1);
    if (has2) m = fmaxf(m, s2);
#pragma unroll
    for (int off = 8; off <= 32; off <<= 1) m = fmaxf(m, __shfl_xor(m, off));
    if ((t & 56) == 0) redM[((t >> 6) << 3) + p] = m;   // one lane per (wave, p)
    __syncthreads();   // B3 (also covers ftl writes)
    float mm = fmaxf(fmaxf(redM[p], redM[8 + p]), fmaxf(redM[16 + p], redM[24 + p]));
    const float e0 = __expf(s0 - mm);
    const float e1 = __expf(s1 - mm);
    const float e2 = has2 ? __expf(s2 - mm) : 0.f;
    simb[k0 * 8 + p] = (_Float16)e0;
    simb[k1 * 8 + p] = (_Float16)e1;
    if (has2) simb[(kb + 64) * 8 + p] = (_Float16)e2;
    float s = e0 + e1 + e2;
#pragma unroll
    for (int off = 8; off <= 32; off <<= 1) s += __shfl_xor(s, off);
    if ((t & 56) == 0) redS[((t >> 6) << 3) + p] = s;
    __syncthreads();   // B4
    const float inv = 1.f / (redS[p] + redS[8 + p] + redS[16 + p] + redS[24 + p]);

    // ---- weighting: thread = (p, cq); 4 channels per thread, fp16 ftl, fp32 accum
    const int cq = t >> 3;
    float4 acc = make_float4(0, 0, 0, 0);
    for (int r = 0; r < 9; ++r) {
        const int rb = ((r << 4) + p) * 136 + (cq << 2);
        const int k9 = r * 9;
#pragma unroll
        for (int dx = 0; dx < 9; ++dx) {
            const float w = (float)simb[(k9 + dx) * 8 + p];  // 8-lane broadcast
            const h4 f = *(const h4*)&ftl[rb + dx * 136];
            acc.x += (float)f[0] * w;
            acc.y += (float)f[1] * w;
            acc.z += (float)f[2] * w;
            acc.w += (float)f[3] * w;
        }
    }
    const size_t ob = (size_t)((nn * Cc + (cq << 2)) << 12) + (y << 6) + x0 + p;
    out[ob]          = acc.x * inv;
    out[ob + HW]     = acc.y * inv;
    out[ob + 2*HW]   = acc.z * inv;
    out[ob + 3*HW]   = acc.w * inv;
}

extern "C" void kernel_launch(void* const* d_in, const int* in_sizes, int n_in,
                              void* d_out, int out_size, void* d_ws, size_t ws_size,
                              hipStream_t stream) {
    const float* ft = (const float*)d_in[0];
    const float* fk = (const float*)d_in[1];
    const float* Wm = (const float*)d_in[2];
    float* out = (float*)d_out;

    _Float16* wsh  = (_Float16*)d_ws;    // 6 MB: Qh(2MB) + Kh(2MB) + fth(2MB)
    _Float16* Qbuf = wsh;                // [p][c]  8192*128 halves
    _Float16* Kbuf = wsh + 1048576;      // [p][c]  8192*128 halves
    _Float16* fth  = wsh + 2097152;      // fp16 ft, PIXEL-MAJOR [p][c]

    proj_kernel<<<256, 256, 0, stream>>>(ft, fk, Wm, Qbuf, Kbuf, fth);
    sim_weight_kernel<<<1024, 256, 0, stream>>>(Qbuf, Kbuf, fth, out);
}

// Round 14
// 79.207 us; speedup vs baseline: 1.2611x; 1.0166x over previous
//
#include <hip/hip_runtime.h>
#include <hip/hip_bf16.h>

// ILA layer (fp32 I/O): key = W@ft, query = W@fk (1x1 conv, shared W),
// sim[p,k] = <query[p], key[neighbor_k(p)]> over 9x9 window (zero-padded keys),
// weight = softmax_k(sim)  (OOB entries participate with sim=0),
// out[c,p] = sum_k weight[k] * ft[c, neighbor_k(p)]  (zero-padded ft).
// n=2, c=128, h=w=64, L=9 (81 neighbors).
// K/Q/ft intermediates fp16. proj = MFMA GEMM (R13-verified layouts).
// sim dots = MFMA banded QK^T: S_r[xx][p], extract band dx=xx-p in [0,9).

#define Hh 64
#define Ww 64
#define Cc 128
#define Nn 2
#define KK 81
#define HW (Hh * Ww)          // 4096
#define CHW (Cc * HW)         // 524288
#define P_TOT (Nn * HW)       // 8192

typedef _Float16 h8 __attribute__((ext_vector_type(8)));
typedef _Float16 h4 __attribute__((ext_vector_type(4)));
typedef float f4v __attribute__((ext_vector_type(4)));

// ---------------- Kernel A: projection via MFMA (R13-measured version, unchanged).
__global__ __launch_bounds__(256) void proj_kernel(const float* __restrict__ ft,
                                                   const float* __restrict__ fk,
                                                   const float* __restrict__ Wm,
                                                   _Float16* __restrict__ Qbuf,
                                                   _Float16* __restrict__ Kbuf,
                                                   _Float16* __restrict__ fth) {
    __shared__ __align__(16) _Float16 Wth[128 * 136];  // [o][i] fp16 (== B[k][n] view)
    __shared__ __align__(16) _Float16 xkh[32 * 136];   // [px][c] fp16
    __shared__ __align__(16) _Float16 xqh[32 * 136];
    const int t = threadIdx.x;
    const int p0 = blockIdx.x * 32;       // 4096 % 32 == 0: never crosses n
    const int nn = p0 >> 12;
    const int gbase = nn * CHW + (p0 & 4095);

#pragma unroll 4
    for (int e = t; e < 4096; e += 256) {             // stage W -> fp16
        const int n = e >> 5, ch = e & 31;
        const float4 v = *(const float4*)&Wm[n * 128 + (ch << 2)];
        h4 hv; hv[0] = (_Float16)v.x; hv[1] = (_Float16)v.y;
               hv[2] = (_Float16)v.z; hv[3] = (_Float16)v.w;
        *(h4*)&Wth[n * 136 + (ch << 2)] = hv;
    }
#pragma unroll 4
    for (int e = t; e < 1024; e += 256) {             // stage x -> fp16 px-major
        const int c = e >> 3, pc = e & 7;
        const float4 vk = *(const float4*)&ft[gbase + c * HW + (pc << 2)];
        const float4 vq = *(const float4*)&fk[gbase + c * HW + (pc << 2)];
        const int px = pc << 2;
        xkh[(px    ) * 136 + c] = (_Float16)vk.x;
        xkh[(px + 1) * 136 + c] = (_Float16)vk.y;
        xkh[(px + 2) * 136 + c] = (_Float16)vk.z;
        xkh[(px + 3) * 136 + c] = (_Float16)vk.w;
        xqh[(px    ) * 136 + c] = (_Float16)vq.x;
        xqh[(px + 1) * 136 + c] = (_Float16)vq.y;
        xqh[(px + 2) * 136 + c] = (_Float16)vq.z;
        xqh[(px + 3) * 136 + c] = (_Float16)vq.w;
    }
    __syncthreads();

#pragma unroll
    for (int e = t; e < 512; e += 256) {              // fth: coalesced h8 copies
        const int px = e >> 4, cq = e & 15;
        *(h8*)&fth[(size_t)(p0 + px) * 128 + (cq << 3)] =
            *(const h8*)&xkh[px * 136 + (cq << 3)];
    }

    const int lane = t & 63, wv = t >> 6;
    const int quad = lane >> 4, l15 = lane & 15;
    const _Float16* xs = (wv >> 1) ? xqh : xkh;
    _Float16* dst = (wv >> 1) ? Qbuf : Kbuf;
    const int mt = wv & 1;
    const int abase = (mt * 16 + l15) * 136 + (quad << 3);
    const h8 a0 = *(const h8*)&xs[abase];
    const h8 a1 = *(const h8*)&xs[abase + 32];
    const h8 a2 = *(const h8*)&xs[abase + 64];
    const h8 a3 = *(const h8*)&xs[abase + 96];
#pragma unroll
    for (int nt = 0; nt < 8; ++nt) {
        const int bbase = (nt * 16 + l15) * 136 + (quad << 3);
        const h8 b0 = *(const h8*)&Wth[bbase];
        const h8 b1 = *(const h8*)&Wth[bbase + 32];
        const h8 b2 = *(const h8*)&Wth[bbase + 64];
        const h8 b3 = *(const h8*)&Wth[bbase + 96];
        f4v acc = {0.f, 0.f, 0.f, 0.f};
        acc = __builtin_amdgcn_mfma_f32_16x16x32_f16(a0, b0, acc, 0, 0, 0);
        acc = __builtin_amdgcn_mfma_f32_16x16x32_f16(a1, b1, acc, 0, 0, 0);
        acc = __builtin_amdgcn_mfma_f32_16x16x32_f16(a2, b2, acc, 0, 0, 0);
        acc = __builtin_amdgcn_mfma_f32_16x16x32_f16(a3, b3, acc, 0, 0, 0);
        const int col = nt * 16 + l15;
        const size_t rb = (size_t)(p0 + mt * 16 + (quad << 2)) * 128 + col;
#pragma unroll
        for (int r = 0; r < 4; ++r)
            dst[rb + (size_t)r * 128] = (_Float16)acc[r];
    }
}

// ---------------- Kernel B (fused): MFMA dots + softmax + weighting. 8-px row strip.
__global__ __launch_bounds__(256, 4) void sim_weight_kernel(const _Float16* __restrict__ Qbuf,
                                                            const _Float16* __restrict__ Kbuf,
                                                            const _Float16* __restrict__ fth,
                                                            float* __restrict__ out) {
    __shared__ __align__(16) unsigned char smem[40720];
    _Float16* Ksw  = (_Float16*)smem;             // 18432 halves [0, 36864)
    _Float16* Qsw  = (_Float16*)(smem + 36864);   // 1024 halves  [36864, 38912)
    _Float16* ftl  = (_Float16*)smem;             // [row][c] stride 136: 19584 halves [0,39168)
    float*    simbF= (float*)smem;                // [k][8] fp32, 2592 B — lives between B2a..B2c (Ksw dead)
    _Float16* simb = (_Float16*)(smem + 39168);   // 648 halves   [39168, 40464)
    float*    redM = (float*)(smem + 40464);      // 32 floats
    float*    redS = (float*)(smem + 40592);      // 32 floats

    const int t  = threadIdx.x;
    const int b  = blockIdx.x;
    const int x0 = (b & 7) << 3;
    const int y  = (b >> 3) & 63;
    const int nn = b >> 9;
    const int pg0 = (nn << 12) + (y << 6) + x0;

    // ---- stage K: zero-padded 9x16 window, h8 copies, XOR-swizzled slots
#pragma unroll 3
    for (int e = t; e < 144 * 16; e += 256) {
        const int v = e >> 4, ci = e & 15;
        const int gx = x0 + (v & 15) - 4;
        const int gy = y + (v >> 4) - 4;
        h8 val = {0, 0, 0, 0, 0, 0, 0, 0};
        if ((unsigned)gx < 64u && (unsigned)gy < 64u)
            val = *(const h8*)&Kbuf[(size_t)((nn << 12) + (gy << 6) + gx) * 128 + (ci << 3)];
        *(h8*)&Ksw[(v << 7) + ((ci ^ (v & 15)) << 3)] = val;
    }
    if (t < 128) {   // stage Q: 8 vectors x 16 chunks
        const int v = t >> 4, ci = t & 15;
        *(h8*)&Qsw[(v << 7) + ((ci ^ v) << 3)] =
            *(const h8*)&Qbuf[(size_t)(pg0 + v) * 128 + (ci << 3)];
    }
    __syncthreads();   // B1

    // ---- dots via MFMA: per r, S_r[xx][p] = sum_c Ksw[r*16+xx][c] * Q[p][c]
    // A = Ksw rows (m=xx via lane&15), B = Qsw rows (n=p via lane&15, row clamped &7),
    // D: row=xx=quad*4+reg, col=p=lane&15 [R13 HW-verified layout].
    const int lane = t & 63, wv = t >> 6;
    const int quad = lane >> 4, l15 = lane & 15;
    const int qrow = l15 & 7;                 // clamp: cols 8-15 duplicate, never extracted
    h8 qb[4];
#pragma unroll
    for (int kc = 0; kc < 4; ++kc) {
        const int ci = (kc << 2) + quad;
        qb[kc] = *(const h8*)&Qsw[(qrow << 7) + ((ci ^ qrow) << 3)];
    }
    const int r0 = wv, r1 = wv + 4;           // r2 = 8 computed by all, extracted by wave 0
    f4v acc0 = {0.f,0.f,0.f,0.f}, acc1 = acc0, acc2 = acc0;
#pragma unroll
    for (int kc = 0; kc < 4; ++kc) {
        const int ci = (kc << 2) + quad;
        const h8 kA = *(const h8*)&Ksw[(((r0 << 4) + l15) << 7) + ((ci ^ l15) << 3)];
        const h8 kB = *(const h8*)&Ksw[(((r1 << 4) + l15) << 7) + ((ci ^ l15) << 3)];
        const h8 kC = *(const h8*)&Ksw[(((8  << 4) + l15) << 7) + ((ci ^ l15) << 3)];
        acc0 = __builtin_amdgcn_mfma_f32_16x16x32_f16(kA, qb[kc], acc0, 0, 0, 0);
        acc1 = __builtin_amdgcn_mfma_f32_16x16x32_f16(kB, qb[kc], acc1, 0, 0, 0);
        acc2 = __builtin_amdgcn_mfma_f32_16x16x32_f16(kC, qb[kc], acc2, 0, 0, 0);
    }
    __syncthreads();   // B2a: all MFMA reads done; Ksw/Qsw dead -> simbF may be written

    // extraction: valid iff p=l15<8 and dx=xx-p in [0,9); k = r*9+dx
#pragma unroll
    for (int reg = 0; reg < 4; ++reg) {
        const int xx = (quad << 2) + reg;
        const int dx = xx - l15;
        const bool ok = (l15 < 8) && (dx >= 0) && (dx < 9);
        if (ok)            simbF[(r0 * 9 + dx) * 8 + l15] = acc0[reg];
        if (ok)            simbF[(r1 * 9 + dx) * 8 + l15] = acc1[reg];
        if (ok && wv == 0) simbF[(8  * 9 + dx) * 8 + l15] = acc2[reg];
    }
    __syncthreads();   // B2b: simbF complete

    const int p = t & 7, kb = t >> 3;
    const bool has2 = (kb + 64 < KK);
    const float s0 = simbF[kb * 8 + p];
    const float s1 = simbF[(kb + 32) * 8 + p];
    const float s2 = has2 ? simbF[(kb + 64) * 8 + p] : 0.f;
    __syncthreads();   // B2c: readback done; ftl may overwrite [0, 39168)

    // ---- restage ft: straight h8 copies fth[pixel] -> ftl[row][c], stride 136
#pragma unroll 3
    for (int e = t; e < 144 * 16; e += 256) {
        const int v = e >> 4, ci = e & 15;
        const int gx = x0 + (v & 15) - 4;
        const int gy = y + (v >> 4) - 4;
        h8 val = {0, 0, 0, 0, 0, 0, 0, 0};
        if ((unsigned)gx < 64u && (unsigned)gy < 64u)
            val = *(const h8*)&fth[(size_t)((nn << 12) + (gy << 6) + gx) * 128 + (ci << 3)];
        *(h8*)&ftl[v * 136 + (ci << 3)] = val;
    }

    // ---- softmax in registers: reduce over lanes sharing p (bits 3..5 of lane id)
    float m = fmaxf(s0, s1);
    if (has2) m = fmaxf(m, s2);
#pragma unroll
    for (int off = 8; off <= 32; off <<= 1) m = fmaxf(m, __shfl_xor(m, off));
    if ((t & 56) == 0) redM[((t >> 6) << 3) + p] = m;   // one lane per (wave, p)
    __syncthreads();   // B3 (also covers ftl writes)
    float mm = fmaxf(fmaxf(redM[p], redM[8 + p]), fmaxf(redM[16 + p], redM[24 + p]));
    const float e0 = __expf(s0 - mm);
    const float e1 = __expf(s1 - mm);
    const float e2 = has2 ? __expf(s2 - mm) : 0.f;
    simb[kb * 8 + p] = (_Float16)e0;
    simb[(kb + 32) * 8 + p] = (_Float16)e1;
    if (has2) simb[(kb + 64) * 8 + p] = (_Float16)e2;
    float s = e0 + e1 + e2;
#pragma unroll
    for (int off = 8; off <= 32; off <<= 1) s += __shfl_xor(s, off);
    if ((t & 56) == 0) redS[((t >> 6) << 3) + p] = s;
    __syncthreads();   // B4
    const float inv = 1.f / (redS[p] + redS[8 + p] + redS[16 + p] + redS[24 + p]);

    // ---- weighting: thread = (p, cq); 4 channels per thread, fp16 ftl, fp32 accum
    const int cq = t >> 3;
    float4 acc = make_float4(0, 0, 0, 0);
    for (int r = 0; r < 9; ++r) {
        const int rb = ((r << 4) + p) * 136 + (cq << 2);
        const int k9 = r * 9;
#pragma unroll
        for (int dx = 0; dx < 9; ++dx) {
            const float w = (float)simb[(k9 + dx) * 8 + p];  // 8-lane broadcast
            const h4 f = *(const h4*)&ftl[rb + dx * 136];
            acc.x += (float)f[0] * w;
            acc.y += (float)f[1] * w;
            acc.z += (float)f[2] * w;
            acc.w += (float)f[3] * w;
        }
    }
    const size_t ob = (size_t)((nn * Cc + (cq << 2)) << 12) + (y << 6) + x0 + p;
    out[ob]          = acc.x * inv;
    out[ob + HW]     = acc.y * inv;
    out[ob + 2*HW]   = acc.z * inv;
    out[ob + 3*HW]   = acc.w * inv;
}

extern "C" void kernel_launch(void* const* d_in, const int* in_sizes, int n_in,
                              void* d_out, int out_size, void* d_ws, size_t ws_size,
                              hipStream_t stream) {
    const float* ft = (const float*)d_in[0];
    const float* fk = (const float*)d_in[1];
    const float* Wm = (const float*)d_in[2];
    float* out = (float*)d_out;

    _Float16* wsh  = (_Float16*)d_ws;    // 6 MB: Qh(2MB) + Kh(2MB) + fth(2MB)
    _Float16* Qbuf = wsh;                // [p][c]  8192*128 halves
    _Float16* Kbuf = wsh + 1048576;      // [p][c]  8192*128 halves
    _Float16* fth  = wsh + 2097152;      // fp16 ft, PIXEL-MAJOR [p][c]

    proj_kernel<<<256, 256, 0, stream>>>(ft, fk, Wm, Qbuf, Kbuf, fth);
    sim_weight_kernel<<<1024, 256, 0, stream>>>(Qbuf, Kbuf, fth, out);
}